// Round 14
// baseline (29.472 us; speedup 1.0000x reference)
//
#include <hip/hip_runtime.h>

// Dilated attention, collapsed form.
// q,k,v: [B=4, D=256, N=8192] f32 (n contiguous). out: [B, N, D] f32.
// HEAD_DIM=32, heads H=8, taps {-2,0,+2} along n, 6 zero-pad softmax slots.
//
// R14: sustained software pipeline. All prior designs are one-shot bursts
// (grid fills the machine exactly once; all load latency exposed as
// ramp+drain). Now 512 blocks x 4 tiles (contiguous 512 n per block):
// two register banks, next tile's 28 loads issue BEFORE current tile's
// compute; vmcnt retires in-order so compute waits only on its own bank
// while the prefetch stays in flight -> 75% of latency overlapped.
// Per-tile math/store identical to R12 (best so far, 25.7us).
// History: R1 43; R2 spill 105; R3 59; R4 41/34b; R5 41; R7 29.3b;
// R8 LDS 36.3b; R9 29.6b; R10 26.3b; R11 27.2b (burst-ILP neutral);
// R12 25.7b (plain stores); R13 27.6b (shuffle halos: chain-lengthening).

constexpr int Bn = 4;
constexpr int Dd = 256;
constexpr int Nn = 8192;
constexpr int HD = 32;
constexpr int Hh = Dd / HD;          // 8
constexpr float SCALE = 0.17677669529663687f;  // 32^-0.5

typedef float vfloat4 __attribute__((ext_vector_type(4)));

struct Tile {
    float4 qv[4], kc[4], vc[4];
    float2 km[4], kp[4], vm[4], vp[4];
};

__device__ __forceinline__ void load_tile(Tile& T,
    const float* __restrict__ q, const float* __restrict__ k,
    const float* __restrict__ v, int cb, bool hasL, bool hasR)
{
    #pragma unroll
    for (int c = 0; c < 4; ++c) {
        const int o = c * Nn;             // uniform -> SGPR base step
        T.qv[c] = *reinterpret_cast<const float4*>(q + cb + o);
        T.kc[c] = *reinterpret_cast<const float4*>(k + cb + o);
        T.vc[c] = *reinterpret_cast<const float4*>(v + cb + o);
        T.km[c] = hasL ? *reinterpret_cast<const float2*>(k + cb + o - 2) : make_float2(0.f, 0.f);
        T.kp[c] = hasR ? *reinterpret_cast<const float2*>(k + cb + o + 4) : make_float2(0.f, 0.f);
        T.vm[c] = hasL ? *reinterpret_cast<const float2*>(v + cb + o - 2) : make_float2(0.f, 0.f);
        T.vp[c] = hasR ? *reinterpret_cast<const float2*>(v + cb + o + 4) : make_float2(0.f, 0.f);
    }
}

__device__ __forceinline__ void compute_store(const Tile& T,
    float* __restrict__ out, int b, int n0, int h, int cg)
{
    // ---- logits for rows n0..n0+3 over this thread's 4 channels ----
    // taps per row j (k[n0+j-2], k[n0+j], k[n0+j+2]):
    //  j=0: km.x kc.x kc.z | j=1: km.y kc.y kc.w
    //  j=2: kc.x kc.z kp.x | j=3: kc.y kc.w kp.y
    float s0[4] = {0.f, 0.f, 0.f, 0.f};
    float s1[4] = {0.f, 0.f, 0.f, 0.f};
    float s2[4] = {0.f, 0.f, 0.f, 0.f};
    #pragma unroll
    for (int c = 0; c < 4; ++c) {
        const float4 qc = T.qv[c];
        const float4 kc = T.kc[c];
        const float2 km = T.km[c];
        const float2 kp = T.kp[c];
        s0[0] = fmaf(qc.x, km.x, s0[0]);
        s1[0] = fmaf(qc.x, kc.x, s1[0]);
        s2[0] = fmaf(qc.x, kc.z, s2[0]);
        s0[1] = fmaf(qc.y, km.y, s0[1]);
        s1[1] = fmaf(qc.y, kc.y, s1[1]);
        s2[1] = fmaf(qc.y, kc.w, s2[1]);
        s0[2] = fmaf(qc.z, kc.x, s0[2]);
        s1[2] = fmaf(qc.z, kc.z, s1[2]);
        s2[2] = fmaf(qc.z, kp.x, s2[2]);
        s0[3] = fmaf(qc.w, kc.y, s0[3]);
        s1[3] = fmaf(qc.w, kc.w, s1[3]);
        s2[3] = fmaf(qc.w, kp.y, s2[3]);
    }

    // reduce across the 8 channel-groups (lane bits 3,4,5); softmax per row
    float p0[4], p1[4], p2[4];
    #pragma unroll
    for (int j = 0; j < 4; ++j) {
        float a = s0[j], bb = s1[j], cc = s2[j];
        a  += __shfl_xor(a,  8, 64); a  += __shfl_xor(a, 16, 64); a  += __shfl_xor(a, 32, 64);
        bb += __shfl_xor(bb, 8, 64); bb += __shfl_xor(bb, 16, 64); bb += __shfl_xor(bb, 32, 64);
        cc += __shfl_xor(cc, 8, 64); cc += __shfl_xor(cc, 16, 64); cc += __shfl_xor(cc, 32, 64);
        a *= SCALE; bb *= SCALE; cc *= SCALE;
        const float m  = fmaxf(fmaxf(a, bb), fmaxf(cc, 0.f));
        const float e0 = __expf(a - m);
        const float e1 = __expf(bb - m);
        const float e2 = __expf(cc - m);
        const float inv = 1.f / (e0 + e1 + e2 + 6.f * __expf(-m));
        p0[j] = e0 * inv; p1[j] = e1 * inv; p2[j] = e2 * inv;
    }

    // ---- PV over 4 channels, one 16 B store per row ----
    float t[4][4];                        // [row j][channel c]
    #pragma unroll
    for (int c = 0; c < 4; ++c) {
        const float4 vc = T.vc[c];
        const float2 vm = T.vm[c];
        const float2 vp = T.vp[c];
        t[0][c] = fmaf(p0[0], vm.x, fmaf(p1[0], vc.x, p2[0] * vc.z));
        t[1][c] = fmaf(p0[1], vm.y, fmaf(p1[1], vc.y, p2[1] * vc.w));
        t[2][c] = fmaf(p0[2], vc.x, fmaf(p1[2], vc.z, p2[2] * vp.x));
        t[3][c] = fmaf(p0[3], vc.y, fmaf(p1[3], vc.w, p2[3] * vp.y));
    }

    // out[b][n0+j][h*32 + cg*4 .. +3]: the wave's 8 channel-groups tile
    // complete 128 B row chunks; plain cached stores (R12 finding).
    float* ob = out + (b * Nn + n0) * Dd + h * HD + cg * 4;
    #pragma unroll
    for (int j = 0; j < 4; ++j) {
        vfloat4 a = {t[j][0], t[j][1], t[j][2], t[j][3]};
        *reinterpret_cast<vfloat4*>(ob + j * Dd) = a;
    }
}

__global__ __launch_bounds__(256) void dilate_attn_kernel(
    const float* __restrict__ q,
    const float* __restrict__ k,
    const float* __restrict__ v,
    float* __restrict__ out)
{
    const int tid  = threadIdx.x;
    const int lane = tid & 63;
    const int subq = lane & 7;            // n-quad within wave (0..7)
    const int cg   = lane >> 3;           // channel group of 4 (0..7)
    const int w    = tid >> 6;            // wave in block (0..3)

    // XCD-chunk swizzle (512 blocks): dispatch i -> XCD i%8; XCD x gets
    // contiguous orig-chunk [x*64, (x+1)*64).
    const int orig = ((blockIdx.x & 7) << 6) + (blockIdx.x >> 3);
    const int bh   = orig >> 4;           // 16 blocks per (b,h)
    const int h    = bh & (Hh - 1);
    const int b    = bh >> 3;
    // block covers 512 n = 4 tiles x 128 n; within a tile: 4 waves x 8 quads x 4 n
    const int nt0 = ((orig & 15) << 9) + (w << 5) + (subq << 2);   // tile-0 n0

    const int cbase = (b * Dd + h * HD + cg * 4) * Nn;   // fits in int

    Tile TA, TB;

    // prologue: tile 0
    load_tile(TA, q, k, v, cbase + nt0, nt0 >= 4, nt0 + 4 < Nn);

    // it=0: prefetch tile 1, compute tile 0
    load_tile(TB, q, k, v, cbase + nt0 + 128, true, nt0 + 132 < Nn);
    compute_store(TA, out, b, nt0, h, cg);

    // it=1: prefetch tile 2, compute tile 1
    load_tile(TA, q, k, v, cbase + nt0 + 256, true, nt0 + 260 < Nn);
    compute_store(TB, out, b, nt0 + 128, h, cg);

    // it=2: prefetch tile 3, compute tile 2
    load_tile(TB, q, k, v, cbase + nt0 + 384, true, nt0 + 388 < Nn);
    compute_store(TA, out, b, nt0 + 256, h, cg);

    // it=3: compute tile 3 (no prefetch)
    compute_store(TB, out, b, nt0 + 384, h, cg);
}

extern "C" void kernel_launch(void* const* d_in, const int* in_sizes, int n_in,
                              void* d_out, int out_size, void* d_ws, size_t ws_size,
                              hipStream_t stream)
{
    const float* q = (const float*)d_in[0];
    const float* k = (const float*)d_in[1];
    const float* v = (const float*)d_in[2];
    float* out = (float*)d_out;

    // 512 blocks x 256 threads; each block covers 512 n of one (b,h).
    dilate_attn_kernel<<<512, 256, 0, stream>>>(q, k, v, out);
}

// Round 15
// 26.201 us; speedup vs baseline: 1.1249x; 1.1249x over previous
//
#include <hip/hip_runtime.h>

// Dilated attention, collapsed form. FINAL (== R12, best of 14 variants).
// q,k,v: [B=4, D=256, N=8192] f32 (n contiguous). out: [B, N, D] f32.
// HEAD_DIM=32, heads H=8, taps {-2,0,+2} along n, 6 zero-pad softmax slots.
//
// Structure: thread = 4 consecutive n x 4 channels; lane = cg*8 + subq;
// all loads (q, k center float4, exact float2 halos, v) issued up-front
// back-to-back (single latency exposure; v arrives during reduce/softmax);
// XCD-chunk blockIdx swizzle for L2 locality; shfl_xor(8|16|32) channel
// reduce; plain cached full-line stores (wave's 8 cgs tile 128 B rows).
// Measured: 25.7us bench, VGPR 44, occ 35%, FETCH 49MB, WRITE 32MB clean.
//
// Bracketing experiments (all worse): R2 forced-occ spill 105; R3 2n/thread
// 144VGPR 59; R4 scalar 58%occ 41/34b; R8 LDS staging 36.3b (halo line-
// fetch + 4-way bank conflict + 15%occ); R9 2x TLP neutral 29.6b; R11 2x
// burst-ILP 27.2b (VGPR 88); R13 shuffle-halos 27.6b (chain-lengthening);
// R14 SW-pipeline 29.5b (VGPR 92, FETCH 59MB). Law: VGPR>~88 -> 27-29.5us;
// VGPR ~44-52 @ ~8 blk/CU -> 25.7-26.3us. 128MB/25.7us = 5.0 TB/s = ~80%
// of pure-copy ceiling; residual = mixed-stream/strided-panel penalty.

constexpr int Bn = 4;
constexpr int Dd = 256;
constexpr int Nn = 8192;
constexpr int HD = 32;
constexpr int Hh = Dd / HD;          // 8
constexpr float SCALE = 0.17677669529663687f;  // 32^-0.5

typedef float vfloat4 __attribute__((ext_vector_type(4)));

__global__ __launch_bounds__(256) void dilate_attn_kernel(
    const float* __restrict__ q,
    const float* __restrict__ k,
    const float* __restrict__ v,
    float* __restrict__ out)
{
    const int tid  = threadIdx.x;
    const int lane = tid & 63;
    const int subq = lane & 7;            // n-quad within wave (0..7)
    const int cg   = lane >> 3;           // channel group of 4 (0..7)
    const int w    = tid >> 6;            // wave in block (0..3)

    // XCD-chunk swizzle: dispatch i lands on XCD i%8; give XCD x the
    // contiguous orig-chunk [x*256, (x+1)*256).
    const int orig = ((blockIdx.x & 7) << 8) + (blockIdx.x >> 3);   // 2048 blocks
    const int bh   = orig >> 6;           // 64 blocks per (b,h)
    const int h    = bh & (Hh - 1);
    const int b    = bh >> 3;
    // block covers 128 n: 4 waves x 8 quads x 4 n
    const int n0 = ((orig & 63) << 7) + (w << 5) + (subq << 2);

    const int cb = (b * Dd + h * HD + cg * 4) * Nn + n0;   // fits in int
    const float* qb = q + cb;
    const float* kb = k + cb;
    const float* vb = v + cb;

    const bool hasL = (n0 >= 4);          // f2 at n0-2 fully in-bounds (n0==0 only fail)
    const bool hasR = (n0 + 4 < Nn);      // f2 at n0+4 fully in-bounds

    // ---- issue ALL loads up-front, back-to-back: q, k(+halo), v(+halo) ----
    float4 qv[4], kc4[4], vc4[4];
    float2 km2[4], kp2[4], vm2[4], vp2[4];
    #pragma unroll
    for (int c = 0; c < 4; ++c) {
        const int o = c * Nn;             // uniform -> SGPR base step
        qv[c] = *reinterpret_cast<const float4*>(qb + o);
    }
    #pragma unroll
    for (int c = 0; c < 4; ++c) {
        const int o = c * Nn;
        kc4[c] = *reinterpret_cast<const float4*>(kb + o);
        km2[c] = hasL ? *reinterpret_cast<const float2*>(kb + o - 2) : make_float2(0.f, 0.f);
        kp2[c] = hasR ? *reinterpret_cast<const float2*>(kb + o + 4) : make_float2(0.f, 0.f);
    }
    #pragma unroll
    for (int c = 0; c < 4; ++c) {
        const int o = c * Nn;
        vc4[c] = *reinterpret_cast<const float4*>(vb + o);
        vm2[c] = hasL ? *reinterpret_cast<const float2*>(vb + o - 2) : make_float2(0.f, 0.f);
        vp2[c] = hasR ? *reinterpret_cast<const float2*>(vb + o + 4) : make_float2(0.f, 0.f);
    }

    // ---- phase 1: partial logits for rows n0..n0+3 over 4 channels ----
    // taps per row j (k[n0+j-2], k[n0+j], k[n0+j+2]):
    //  j=0: km.x kc.x kc.z | j=1: km.y kc.y kc.w
    //  j=2: kc.x kc.z kp.x | j=3: kc.y kc.w kp.y
    float s0[4] = {0.f, 0.f, 0.f, 0.f};
    float s1[4] = {0.f, 0.f, 0.f, 0.f};
    float s2[4] = {0.f, 0.f, 0.f, 0.f};
    #pragma unroll
    for (int c = 0; c < 4; ++c) {
        const float4 qc = qv[c];
        const float4 kc = kc4[c];
        const float2 km = km2[c];
        const float2 kp = kp2[c];
        s0[0] = fmaf(qc.x, km.x, s0[0]);
        s1[0] = fmaf(qc.x, kc.x, s1[0]);
        s2[0] = fmaf(qc.x, kc.z, s2[0]);
        s0[1] = fmaf(qc.y, km.y, s0[1]);
        s1[1] = fmaf(qc.y, kc.y, s1[1]);
        s2[1] = fmaf(qc.y, kc.w, s2[1]);
        s0[2] = fmaf(qc.z, kc.x, s0[2]);
        s1[2] = fmaf(qc.z, kc.z, s1[2]);
        s2[2] = fmaf(qc.z, kp.x, s2[2]);
        s0[3] = fmaf(qc.w, kc.y, s0[3]);
        s1[3] = fmaf(qc.w, kc.w, s1[3]);
        s2[3] = fmaf(qc.w, kp.y, s2[3]);
    }

    // reduce across the 8 channel-groups (lane bits 3,4,5); softmax per row.
    // v-loads are completing in the background during this whole phase.
    float p0[4], p1[4], p2[4];
    #pragma unroll
    for (int j = 0; j < 4; ++j) {
        float a = s0[j], bb = s1[j], cc = s2[j];
        a  += __shfl_xor(a,  8, 64); a  += __shfl_xor(a, 16, 64); a  += __shfl_xor(a, 32, 64);
        bb += __shfl_xor(bb, 8, 64); bb += __shfl_xor(bb, 16, 64); bb += __shfl_xor(bb, 32, 64);
        cc += __shfl_xor(cc, 8, 64); cc += __shfl_xor(cc, 16, 64); cc += __shfl_xor(cc, 32, 64);
        a *= SCALE; bb *= SCALE; cc *= SCALE;
        const float m  = fmaxf(fmaxf(a, bb), fmaxf(cc, 0.f));
        const float e0 = __expf(a - m);
        const float e1 = __expf(bb - m);
        const float e2 = __expf(cc - m);
        const float inv = 1.f / (e0 + e1 + e2 + 6.f * __expf(-m));
        p0[j] = e0 * inv; p1[j] = e1 * inv; p2[j] = e2 * inv;
    }

    // ---- phase 3: PV over 4 channels (v already resident), 16 B store/row ----
    float t[4][4];                        // [row j][channel c]
    #pragma unroll
    for (int c = 0; c < 4; ++c) {
        const float4 vc = vc4[c];
        const float2 vm = vm2[c];
        const float2 vp = vp2[c];
        t[0][c] = fmaf(p0[0], vm.x, fmaf(p1[0], vc.x, p2[0] * vc.z));
        t[1][c] = fmaf(p0[1], vm.y, fmaf(p1[1], vc.y, p2[1] * vc.w));
        t[2][c] = fmaf(p0[2], vc.x, fmaf(p1[2], vc.z, p2[2] * vp.x));
        t[3][c] = fmaf(p0[3], vc.y, fmaf(p1[3], vc.w, p2[3] * vp.y));
    }

    // out[b][n0+j][h*32 + cg*4 .. +3]: 16 B per lane per row; the wave's
    // 8 channel-groups tile complete 128 B row chunks. Plain cached stores.
    float* ob = out + (b * Nn + n0) * Dd + h * HD + cg * 4;
    #pragma unroll
    for (int j = 0; j < 4; ++j) {
        vfloat4 a = {t[j][0], t[j][1], t[j][2], t[j][3]};
        *reinterpret_cast<vfloat4*>(ob + j * Dd) = a;
    }
}

extern "C" void kernel_launch(void* const* d_in, const int* in_sizes, int n_in,
                              void* d_out, int out_size, void* d_ws, size_t ws_size,
                              hipStream_t stream)
{
    const float* q = (const float*)d_in[0];
    const float* k = (const float*)d_in[1];
    const float* v = (const float*)d_in[2];
    float* out = (float*)d_out;

    // B*H*(N/4) quads x 8 channel-groups = 524288 threads = 2048 blocks
    const int total_threads = Bn * Hh * (Nn / 4) * 8;
    dilate_attn_kernel<<<total_threads / 256, 256, 0, stream>>>(q, k, v, out);
}